// Round 6
// baseline (121.094 us; speedup 1.0000x reference)
//
#include <hip/hip_runtime.h>

// RoiPoolingConv: fm [64,64,1024] f32 NHWC, rois [300,4] int32 (x,y,w,h),
// out [300,14,14,1024] f32.
//
//  1. sort_items: counting-sort 4200 (roi,py) items by y0 into perm (d_ws).
//  2. roi_pool_row_kernel: one block per item, 256 threads x float4 over
//     1024 channels, loop px. y0-sorted + bijective XCD swizzle -> per-XCD
//     L2 read locality. NT stores keep the 241 MB output out of L2.
//     NEW: NT (no-allocate) LOADS — corner reads have ~no L1 reuse, and an
//     L1-missing read pays the CU's vector port twice (fill + return).
//     nt loads deliver L2->VGPR in one pass -> read port cost halves.

#define POOL 14
#define FMW 64
#define CH 1024
#define C4 (CH / 4)        // 256 float4 per pixel
#define MAX_ITEMS (300 * POOL)

typedef float f4 __attribute__((ext_vector_type(4)));

__global__ __launch_bounds__(1024) void sort_items_kernel(
    const int* __restrict__ rois, int num_rois, int* __restrict__ perm)
{
    __shared__ int   base[64];
    __shared__ short s_y0[MAX_ITEMS];
    __shared__ int   s_yh[600];          // (y,h) per roi
    const int tid = threadIdx.x;
    const int num_items = num_rois * POOL;

    if (tid < 64) base[tid] = 0;
    for (int i = tid; i < num_rois; i += blockDim.x) {
        s_yh[i * 2]     = rois[i * 4 + 1];
        s_yh[i * 2 + 1] = rois[i * 4 + 3];
    }
    __syncthreads();

    for (int i = tid; i < num_items; i += blockDim.x) {
        const int roi = i / POOL, py = i % POOL;
        const int y = s_yh[roi * 2], h = s_yh[roi * 2 + 1];
        const float fy = (float)y + (float)py * ((float)h * (1.0f / 14.0f));
        const int y0 = (int)floorf(fy) & 63;
        s_y0[i] = (short)y0;
        atomicAdd(&base[y0], 1);
    }
    __syncthreads();

    if (tid < 64) {
        const int orig = base[tid];
        int v = orig;
        #pragma unroll
        for (int d = 1; d < 64; d <<= 1) {
            const int t = __shfl_up(v, d, 64);
            if (tid >= d) v += t;
        }
        base[tid] = v - orig;
    }
    __syncthreads();

    for (int i = tid; i < num_items; i += blockDim.x) {
        const int pos = atomicAdd(&base[(int)s_y0[i]], 1);
        perm[pos] = i;
    }
}

__global__ __launch_bounds__(256) void roi_pool_row_kernel(
    const float* __restrict__ fm,
    const int* __restrict__ rois,
    const int* __restrict__ perm,
    int nw,
    float* __restrict__ out)
{
    // bijective XCD swizzle (nw % 8 == 0): XCD j gets a contiguous y0 band
    const int per = nw >> 3;
    const int b   = blockIdx.x;
    const int sb  = (b & 7) * per + (b >> 3);
    const int item = perm[sb];

    const int py  = item % POOL;
    const int roi = item / POOL;

    const int4 r = *reinterpret_cast<const int4*>(rois + roi * 4);
    const int x = r.x, y = r.y, w = r.z, h = r.w;

    // Legacy-TF bilinear (align_corners=False, no half-pixel centers)
    const float fy = (float)y + (float)py * ((float)h * (1.0f / 14.0f));
    const int   y0 = (int)floorf(fy);
    const int   y1 = min(y0 + 1, y + h - 1);
    const float wy = fy - (float)y0;

    const int c = threadIdx.x;  // float4 lane over channels
    const f4* row0 = reinterpret_cast<const f4*>(fm) + (size_t)(y0 * FMW) * C4 + c;
    const f4* row1 = reinterpret_cast<const f4*>(fm) + (size_t)(y1 * FMW) * C4 + c;
    f4* op = reinterpret_cast<f4*>(out) + (size_t)((roi * POOL + py) * POOL) * C4 + c;

    const float wscale = (float)w * (1.0f / 14.0f);
    const int   xmax   = x + w - 1;

    // ---- software pipeline, 1 iteration deep; all reads non-temporal ----
    const int x1p = min(x + 1, xmax);
    f4 a_tl = __builtin_nontemporal_load(row0 + (size_t)x * C4);
    f4 a_tr = __builtin_nontemporal_load(row0 + (size_t)x1p * C4);
    f4 a_bl = __builtin_nontemporal_load(row1 + (size_t)x * C4);
    f4 a_br = __builtin_nontemporal_load(row1 + (size_t)x1p * C4);
    float a_wx = 0.0f;

    #pragma unroll 1
    for (int px = 0; px < POOL - 1; ++px) {
        const float fx  = (float)x + (float)(px + 1) * wscale;
        const int   x0  = (int)floorf(fx);
        const int   x1  = min(x0 + 1, xmax);
        const float nwx = fx - (float)x0;
        const f4 n_tl = __builtin_nontemporal_load(row0 + (size_t)x0 * C4);
        const f4 n_tr = __builtin_nontemporal_load(row0 + (size_t)x1 * C4);
        const f4 n_bl = __builtin_nontemporal_load(row1 + (size_t)x0 * C4);
        const f4 n_br = __builtin_nontemporal_load(row1 + (size_t)x1 * C4);

        const f4 top = a_tl + a_wx * (a_tr - a_tl);
        const f4 bot = a_bl + a_wx * (a_br - a_bl);
        const f4 o   = top + wy * (bot - top);
        __builtin_nontemporal_store(o, op + (size_t)px * C4);

        a_tl = n_tl; a_tr = n_tr; a_bl = n_bl; a_br = n_br; a_wx = nwx;
    }
    {
        const f4 top = a_tl + a_wx * (a_tr - a_tl);
        const f4 bot = a_bl + a_wx * (a_br - a_bl);
        const f4 o   = top + wy * (bot - top);
        __builtin_nontemporal_store(o, op + (size_t)(POOL - 1) * C4);
    }
}

// Fallback without permutation (identity order).
__global__ __launch_bounds__(256) void roi_pool_row_kernel_noperm(
    const float* __restrict__ fm,
    const int* __restrict__ rois,
    int nw,
    float* __restrict__ out)
{
    const int sb  = blockIdx.x;
    const int py  = sb % POOL;
    const int roi = sb / POOL;

    const int4 r = *reinterpret_cast<const int4*>(rois + roi * 4);
    const int x = r.x, y = r.y, w = r.z, h = r.w;

    const float fy = (float)y + (float)py * ((float)h * (1.0f / 14.0f));
    const int   y0 = (int)floorf(fy);
    const int   y1 = min(y0 + 1, y + h - 1);
    const float wy = fy - (float)y0;

    const int c = threadIdx.x;
    const f4* row0 = reinterpret_cast<const f4*>(fm) + (size_t)(y0 * FMW) * C4 + c;
    const f4* row1 = reinterpret_cast<const f4*>(fm) + (size_t)(y1 * FMW) * C4 + c;
    f4* op = reinterpret_cast<f4*>(out) + (size_t)((roi * POOL + py) * POOL) * C4 + c;

    const float wscale = (float)w * (1.0f / 14.0f);
    const int   xmax   = x + w - 1;

    for (int px = 0; px < POOL; ++px) {
        const float fx = (float)x + (float)px * wscale;
        const int   x0 = (int)floorf(fx);
        const int   x1 = min(x0 + 1, xmax);
        const float wx = fx - (float)x0;

        const f4 tl = __builtin_nontemporal_load(row0 + (size_t)x0 * C4);
        const f4 tr = __builtin_nontemporal_load(row0 + (size_t)x1 * C4);
        const f4 bl = __builtin_nontemporal_load(row1 + (size_t)x0 * C4);
        const f4 br = __builtin_nontemporal_load(row1 + (size_t)x1 * C4);

        const f4 top = tl + wx * (tr - tl);
        const f4 bot = bl + wx * (br - bl);
        const f4 o   = top + wy * (bot - top);

        __builtin_nontemporal_store(o, op + (size_t)px * C4);
    }
}

extern "C" void kernel_launch(void* const* d_in, const int* in_sizes, int n_in,
                              void* d_out, int out_size, void* d_ws, size_t ws_size,
                              hipStream_t stream) {
    const float* fm  = (const float*)d_in[0];   // [1,64,64,1024] f32
    const int* rois  = (const int*)d_in[1];     // [1,300,4] i32
    float* out       = (float*)d_out;           // [1,300,14,14,1024] f32

    const int num_rois = in_sizes[1] / 4;       // 300
    const int nw = num_rois * POOL;             // 4200 work items

    if (ws_size >= (size_t)nw * sizeof(int) && (nw & 7) == 0 && nw <= MAX_ITEMS) {
        int* perm = (int*)d_ws;
        sort_items_kernel<<<1, 1024, 0, stream>>>(rois, num_rois, perm);
        roi_pool_row_kernel<<<nw, 256, 0, stream>>>(fm, rois, perm, nw, out);
    } else {
        roi_pool_row_kernel_noperm<<<nw, 256, 0, stream>>>(fm, rois, nw, out);
    }
}

// Round 7
// 68.413 us; speedup vs baseline: 1.7700x; 1.7700x over previous
//
#include <hip/hip_runtime.h>

// RoiPoolingConv: fm [64,64,1024] f32 NHWC, rois [300,4] int32 (x,y,w,h),
// out [300,14,14,1024] f32.
//
//  1. sort_items: counting-sort 4200 (roi,py) items by y0 into perm (d_ws).
//  2. roi_pool_col_kernel: one block per item, 256 threads x float4 over
//     1024 channels. NEW STRUCTURE: loop over the ROI row's DISTINCT source
//     columns (w iterations, 2 loads each = ~34 loads avg vs 56 for the
//     4-corner-per-px scheme), blend top/bot with wy once per column, and
//     accumulate into 14 static f4 accumulators with wave-uniform scalar
//     guards (x0/x1 from readfirstlane -> s_cmp/s_cbranch, loads stay
//     unconditional). Cuts L1-port transactions ~35% (misses pay the port
//     twice: fill + return). NT stores burst at the end; loads stay
//     L2-allocating (R6 proved nt loads fall through L2 -> 2x regression).

#define POOL 14
#define FMW 64
#define CH 1024
#define C4 (CH / 4)        // 256 float4 per pixel
#define MAX_ITEMS (300 * POOL)

typedef float f4 __attribute__((ext_vector_type(4)));

__global__ __launch_bounds__(1024) void sort_items_kernel(
    const int* __restrict__ rois, int num_rois, int* __restrict__ perm)
{
    __shared__ int   base[64];
    __shared__ short s_y0[MAX_ITEMS];
    __shared__ int   s_yh[600];          // (y,h) per roi
    const int tid = threadIdx.x;
    const int num_items = num_rois * POOL;

    if (tid < 64) base[tid] = 0;
    for (int i = tid; i < num_rois; i += blockDim.x) {
        s_yh[i * 2]     = rois[i * 4 + 1];
        s_yh[i * 2 + 1] = rois[i * 4 + 3];
    }
    __syncthreads();

    for (int i = tid; i < num_items; i += blockDim.x) {
        const int roi = i / POOL, py = i % POOL;
        const int y = s_yh[roi * 2], h = s_yh[roi * 2 + 1];
        const float fy = (float)y + (float)py * ((float)h * (1.0f / 14.0f));
        const int y0 = (int)floorf(fy) & 63;
        s_y0[i] = (short)y0;
        atomicAdd(&base[y0], 1);
    }
    __syncthreads();

    if (tid < 64) {
        const int orig = base[tid];
        int v = orig;
        #pragma unroll
        for (int d = 1; d < 64; d <<= 1) {
            const int t = __shfl_up(v, d, 64);
            if (tid >= d) v += t;
        }
        base[tid] = v - orig;
    }
    __syncthreads();

    for (int i = tid; i < num_items; i += blockDim.x) {
        const int pos = atomicAdd(&base[(int)s_y0[i]], 1);
        perm[pos] = i;
    }
}

__global__ __launch_bounds__(256) void roi_pool_col_kernel(
    const float* __restrict__ fm,
    const int* __restrict__ rois,
    const int* __restrict__ perm,
    int nw,
    float* __restrict__ out)
{
    // bijective XCD swizzle (nw % 8 == 0): XCD j gets a contiguous y0 band
    const int per = nw >> 3;
    const int b   = blockIdx.x;
    const int sb  = (b & 7) * per + (b >> 3);
    const int item = __builtin_amdgcn_readfirstlane(perm[sb]);

    const int py  = item % POOL;
    const int roi = item / POOL;

    const int4 r = *reinterpret_cast<const int4*>(rois + roi * 4);
    const int x = __builtin_amdgcn_readfirstlane(r.x);
    const int y = __builtin_amdgcn_readfirstlane(r.y);
    const int w = __builtin_amdgcn_readfirstlane(r.z);
    const int h = __builtin_amdgcn_readfirstlane(r.w);

    // Legacy-TF bilinear (align_corners=False, no half-pixel centers)
    const float fy = (float)y + (float)py * ((float)h * (1.0f / 14.0f));
    const int   y0 = __builtin_amdgcn_readfirstlane((int)floorf(fy));
    const int   y1 = min(y0 + 1, y + h - 1);
    const float wy = fy - (float)y0;

    const int c = threadIdx.x;  // float4 lane over channels
    const f4* row0 = reinterpret_cast<const f4*>(fm) + (size_t)(y0 * FMW) * C4 + c;
    const f4* row1 = reinterpret_cast<const f4*>(fm) + (size_t)(y1 * FMW) * C4 + c;
    f4* op = reinterpret_cast<f4*>(out) + (size_t)((roi * POOL + py) * POOL) * C4 + c;

    const float wscale = (float)w * (1.0f / 14.0f);
    const int   xmax   = x + w - 1;

    // per-px bilinear x data (all wave-uniform scalars)
    int   x0a[POOL], x1a[POOL];
    float wxa[POOL];
    #pragma unroll
    for (int px = 0; px < POOL; ++px) {
        const float fx = (float)x + (float)px * wscale;
        const int   x0 = (int)floorf(fx);
        x0a[px] = x0;
        x1a[px] = min(x0 + 1, xmax);
        wxa[px] = fx - (float)x0;
    }

    // 14 output accumulators (static indices only)
    f4 acc[POOL];
    #pragma unroll
    for (int px = 0; px < POOL; ++px) acc[px] = (f4){0.f, 0.f, 0.f, 0.f};

    // column loop: process cx with data (ptop,pbot), prefetch cx+1
    f4 ptop = row0[(size_t)x * C4];
    f4 pbot = row1[(size_t)x * C4];

    for (int cx = x; cx <= xmax; ++cx) {
        f4 ntop, nbot;
        if (cx < xmax) {
            ntop = row0[(size_t)(cx + 1) * C4];
            nbot = row1[(size_t)(cx + 1) * C4];
        }

        const f4 v = ptop + wy * (pbot - ptop);   // y-blend once per column

        #pragma unroll
        for (int px = 0; px < POOL; ++px) {
            const bool h0 = (x0a[px] == cx);
            const bool h1 = (x1a[px] == cx);
            if (h0 || h1) {
                const float wt = (h0 ? 1.0f - wxa[px] : 0.0f) + (h1 ? wxa[px] : 0.0f);
                acc[px] += wt * v;
            }
        }

        ptop = ntop; pbot = nbot;
    }

    #pragma unroll
    for (int px = 0; px < POOL; ++px)
        __builtin_nontemporal_store(acc[px], op + (size_t)px * C4);
}

// Fallback without permutation (identity order), simple 4-corner loop.
__global__ __launch_bounds__(256) void roi_pool_row_kernel_noperm(
    const float* __restrict__ fm,
    const int* __restrict__ rois,
    int nw,
    float* __restrict__ out)
{
    const int sb  = blockIdx.x;
    const int py  = sb % POOL;
    const int roi = sb / POOL;

    const int4 r = *reinterpret_cast<const int4*>(rois + roi * 4);
    const int x = r.x, y = r.y, w = r.z, h = r.w;

    const float fy = (float)y + (float)py * ((float)h * (1.0f / 14.0f));
    const int   y0 = (int)floorf(fy);
    const int   y1 = min(y0 + 1, y + h - 1);
    const float wy = fy - (float)y0;

    const int c = threadIdx.x;
    const f4* row0 = reinterpret_cast<const f4*>(fm) + (size_t)(y0 * FMW) * C4 + c;
    const f4* row1 = reinterpret_cast<const f4*>(fm) + (size_t)(y1 * FMW) * C4 + c;
    f4* op = reinterpret_cast<f4*>(out) + (size_t)((roi * POOL + py) * POOL) * C4 + c;

    const float wscale = (float)w * (1.0f / 14.0f);
    const int   xmax   = x + w - 1;

    for (int px = 0; px < POOL; ++px) {
        const float fx = (float)x + (float)px * wscale;
        const int   x0 = (int)floorf(fx);
        const int   x1 = min(x0 + 1, xmax);
        const float wx = fx - (float)x0;

        const f4 tl = row0[(size_t)x0 * C4];
        const f4 tr = row0[(size_t)x1 * C4];
        const f4 bl = row1[(size_t)x0 * C4];
        const f4 br = row1[(size_t)x1 * C4];

        const f4 top = tl + wx * (tr - tl);
        const f4 bot = bl + wx * (br - bl);
        const f4 o   = top + wy * (bot - top);

        __builtin_nontemporal_store(o, op + (size_t)px * C4);
    }
}

extern "C" void kernel_launch(void* const* d_in, const int* in_sizes, int n_in,
                              void* d_out, int out_size, void* d_ws, size_t ws_size,
                              hipStream_t stream) {
    const float* fm  = (const float*)d_in[0];   // [1,64,64,1024] f32
    const int* rois  = (const int*)d_in[1];     // [1,300,4] i32
    float* out       = (float*)d_out;           // [1,300,14,14,1024] f32

    const int num_rois = in_sizes[1] / 4;       // 300
    const int nw = num_rois * POOL;             // 4200 work items

    if (ws_size >= (size_t)nw * sizeof(int) && (nw & 7) == 0 && nw <= MAX_ITEMS) {
        int* perm = (int*)d_ws;
        sort_items_kernel<<<1, 1024, 0, stream>>>(rois, num_rois, perm);
        roi_pool_col_kernel<<<nw, 256, 0, stream>>>(fm, rois, perm, nw, out);
    } else {
        roi_pool_row_kernel_noperm<<<nw, 256, 0, stream>>>(fm, rois, nw, out);
    }
}

// Round 8
// 54.122 us; speedup vs baseline: 2.2374x; 1.2640x over previous
//
#include <hip/hip_runtime.h>

// RoiPoolingConv: fm [64,64,1024] f32 NHWC, rois [300,4] int32 (x,y,w,h),
// out [300,14,14,1024] f32.
//
//  1. sort_items: counting-sort 4200 (roi,py) items by y0 into perm (d_ws).
//  2. roi_pool_row_kernel: one block per item, 256 threads x float4 over
//     1024 channels, loop px; 1-deep software pipeline. y0-sorted +
//     bijective XCD swizzle -> per-XCD L2 read locality.
//     A/B THIS ROUND: PLAIN stores (L2-allocating) instead of NT stores.
//     Theory: NT stores bypass the L2 write-coalescing path and sustain
//     only ~4.4 TB/s (241MB/55us observed); the harness fill kernel's plain
//     stores sustain 6.9 TB/s. Reads (~1MB hot band per XCD, high re-touch)
//     should survive streaming-write eviction via LRU.

#define POOL 14
#define FMW 64
#define CH 1024
#define C4 (CH / 4)        // 256 float4 per pixel
#define MAX_ITEMS (300 * POOL)

typedef float f4 __attribute__((ext_vector_type(4)));

__global__ __launch_bounds__(1024) void sort_items_kernel(
    const int* __restrict__ rois, int num_rois, int* __restrict__ perm)
{
    __shared__ int   base[64];
    __shared__ short s_y0[MAX_ITEMS];
    __shared__ int   s_yh[600];          // (y,h) per roi
    const int tid = threadIdx.x;
    const int num_items = num_rois * POOL;

    if (tid < 64) base[tid] = 0;
    for (int i = tid; i < num_rois; i += blockDim.x) {
        s_yh[i * 2]     = rois[i * 4 + 1];
        s_yh[i * 2 + 1] = rois[i * 4 + 3];
    }
    __syncthreads();

    for (int i = tid; i < num_items; i += blockDim.x) {
        const int roi = i / POOL, py = i % POOL;
        const int y = s_yh[roi * 2], h = s_yh[roi * 2 + 1];
        const float fy = (float)y + (float)py * ((float)h * (1.0f / 14.0f));
        const int y0 = (int)floorf(fy) & 63;
        s_y0[i] = (short)y0;
        atomicAdd(&base[y0], 1);
    }
    __syncthreads();

    if (tid < 64) {
        const int orig = base[tid];
        int v = orig;
        #pragma unroll
        for (int d = 1; d < 64; d <<= 1) {
            const int t = __shfl_up(v, d, 64);
            if (tid >= d) v += t;
        }
        base[tid] = v - orig;
    }
    __syncthreads();

    for (int i = tid; i < num_items; i += blockDim.x) {
        const int pos = atomicAdd(&base[(int)s_y0[i]], 1);
        perm[pos] = i;
    }
}

__global__ __launch_bounds__(256) void roi_pool_row_kernel(
    const float* __restrict__ fm,
    const int* __restrict__ rois,
    const int* __restrict__ perm,
    int nw,
    float* __restrict__ out)
{
    // bijective XCD swizzle (nw % 8 == 0): XCD j gets a contiguous y0 band
    const int per = nw >> 3;
    const int b   = blockIdx.x;
    const int sb  = (b & 7) * per + (b >> 3);
    const int item = perm[sb];

    const int py  = item % POOL;
    const int roi = item / POOL;

    const int4 r = *reinterpret_cast<const int4*>(rois + roi * 4);
    const int x = r.x, y = r.y, w = r.z, h = r.w;

    // Legacy-TF bilinear (align_corners=False, no half-pixel centers)
    const float fy = (float)y + (float)py * ((float)h * (1.0f / 14.0f));
    const int   y0 = (int)floorf(fy);
    const int   y1 = min(y0 + 1, y + h - 1);
    const float wy = fy - (float)y0;

    const int c = threadIdx.x;  // float4 lane over channels
    const f4* row0 = reinterpret_cast<const f4*>(fm) + (size_t)(y0 * FMW) * C4 + c;
    const f4* row1 = reinterpret_cast<const f4*>(fm) + (size_t)(y1 * FMW) * C4 + c;
    f4* op = reinterpret_cast<f4*>(out) + (size_t)((roi * POOL + py) * POOL) * C4 + c;

    const float wscale = (float)w * (1.0f / 14.0f);
    const int   xmax   = x + w - 1;

    // ---- software pipeline, 1 iteration deep ----
    const int x1p = min(x + 1, xmax);
    f4 a_tl = row0[(size_t)x * C4];
    f4 a_tr = row0[(size_t)x1p * C4];
    f4 a_bl = row1[(size_t)x * C4];
    f4 a_br = row1[(size_t)x1p * C4];
    float a_wx = 0.0f;

    #pragma unroll 1
    for (int px = 0; px < POOL - 1; ++px) {
        const float fx  = (float)x + (float)(px + 1) * wscale;
        const int   x0  = (int)floorf(fx);
        const int   x1  = min(x0 + 1, xmax);
        const float nwx = fx - (float)x0;
        const f4 n_tl = row0[(size_t)x0 * C4];
        const f4 n_tr = row0[(size_t)x1 * C4];
        const f4 n_bl = row1[(size_t)x0 * C4];
        const f4 n_br = row1[(size_t)x1 * C4];

        const f4 top = a_tl + a_wx * (a_tr - a_tl);
        const f4 bot = a_bl + a_wx * (a_br - a_bl);
        const f4 o   = top + wy * (bot - top);
        op[(size_t)px * C4] = o;                 // plain (L2-allocating) store

        a_tl = n_tl; a_tr = n_tr; a_bl = n_bl; a_br = n_br; a_wx = nwx;
    }
    {
        const f4 top = a_tl + a_wx * (a_tr - a_tl);
        const f4 bot = a_bl + a_wx * (a_br - a_bl);
        const f4 o   = top + wy * (bot - top);
        op[(size_t)(POOL - 1) * C4] = o;         // plain store
    }
}

// Fallback without permutation (identity order).
__global__ __launch_bounds__(256) void roi_pool_row_kernel_noperm(
    const float* __restrict__ fm,
    const int* __restrict__ rois,
    int nw,
    float* __restrict__ out)
{
    const int sb  = blockIdx.x;
    const int py  = sb % POOL;
    const int roi = sb / POOL;

    const int4 r = *reinterpret_cast<const int4*>(rois + roi * 4);
    const int x = r.x, y = r.y, w = r.z, h = r.w;

    const float fy = (float)y + (float)py * ((float)h * (1.0f / 14.0f));
    const int   y0 = (int)floorf(fy);
    const int   y1 = min(y0 + 1, y + h - 1);
    const float wy = fy - (float)y0;

    const int c = threadIdx.x;
    const f4* row0 = reinterpret_cast<const f4*>(fm) + (size_t)(y0 * FMW) * C4 + c;
    const f4* row1 = reinterpret_cast<const f4*>(fm) + (size_t)(y1 * FMW) * C4 + c;
    f4* op = reinterpret_cast<f4*>(out) + (size_t)((roi * POOL + py) * POOL) * C4 + c;

    const float wscale = (float)w * (1.0f / 14.0f);
    const int   xmax   = x + w - 1;

    for (int px = 0; px < POOL; ++px) {
        const float fx = (float)x + (float)px * wscale;
        const int   x0 = (int)floorf(fx);
        const int   x1 = min(x0 + 1, xmax);
        const float wx = fx - (float)x0;

        const f4 tl = row0[(size_t)x0 * C4];
        const f4 tr = row0[(size_t)x1 * C4];
        const f4 bl = row1[(size_t)x0 * C4];
        const f4 br = row1[(size_t)x1 * C4];

        const f4 top = tl + wx * (tr - tl);
        const f4 bot = bl + wx * (br - bl);
        const f4 o   = top + wy * (bot - top);

        op[(size_t)px * C4] = o;
    }
}

extern "C" void kernel_launch(void* const* d_in, const int* in_sizes, int n_in,
                              void* d_out, int out_size, void* d_ws, size_t ws_size,
                              hipStream_t stream) {
    const float* fm  = (const float*)d_in[0];   // [1,64,64,1024] f32
    const int* rois  = (const int*)d_in[1];     // [1,300,4] i32
    float* out       = (float*)d_out;           // [1,300,14,14,1024] f32

    const int num_rois = in_sizes[1] / 4;       // 300
    const int nw = num_rois * POOL;             // 4200 work items

    if (ws_size >= (size_t)nw * sizeof(int) && (nw & 7) == 0 && nw <= MAX_ITEMS) {
        int* perm = (int*)d_ws;
        sort_items_kernel<<<1, 1024, 0, stream>>>(rois, num_rois, perm);
        roi_pool_row_kernel<<<nw, 256, 0, stream>>>(fm, rois, perm, nw, out);
    } else {
        roi_pool_row_kernel_noperm<<<nw, 256, 0, stream>>>(fm, rois, nw, out);
    }
}

// Round 9
// 53.979 us; speedup vs baseline: 2.2433x; 1.0026x over previous
//
#include <hip/hip_runtime.h>

// RoiPoolingConv: fm [64,64,1024] f32 NHWC, rois [300,4] int32 (x,y,w,h),
// out [300,14,14,1024] f32.
//
//  1. sort_items: counting-sort 4200 (roi,py) items by y0 into perm (d_ws).
//  2. roi_pool_row_kernel: one block per item, 256 threads x float4 over
//     1024 channels, loop px. y0-sorted + bijective XCD swizzle -> per-XCD
//     L2 read locality. Plain stores (R8: NT stores cost ~6.5us -- the
//     L2-bypass store path sustains only ~4.4 TB/s vs 6.9 through L2).
//     THIS ROUND: 2-deep software pipeline (8 loads outstanding) so the
//     px-store issue is never gated by the px-loads' L2 latency (~300cy).

#define POOL 14
#define FMW 64
#define CH 1024
#define C4 (CH / 4)        // 256 float4 per pixel
#define MAX_ITEMS (300 * POOL)

typedef float f4 __attribute__((ext_vector_type(4)));

__global__ __launch_bounds__(1024) void sort_items_kernel(
    const int* __restrict__ rois, int num_rois, int* __restrict__ perm)
{
    __shared__ int   base[64];
    __shared__ short s_y0[MAX_ITEMS];
    __shared__ int   s_yh[600];          // (y,h) per roi
    const int tid = threadIdx.x;
    const int num_items = num_rois * POOL;

    if (tid < 64) base[tid] = 0;
    for (int i = tid; i < num_rois; i += blockDim.x) {
        s_yh[i * 2]     = rois[i * 4 + 1];
        s_yh[i * 2 + 1] = rois[i * 4 + 3];
    }
    __syncthreads();

    for (int i = tid; i < num_items; i += blockDim.x) {
        const int roi = i / POOL, py = i % POOL;
        const int y = s_yh[roi * 2], h = s_yh[roi * 2 + 1];
        const float fy = (float)y + (float)py * ((float)h * (1.0f / 14.0f));
        const int y0 = (int)floorf(fy) & 63;
        s_y0[i] = (short)y0;
        atomicAdd(&base[y0], 1);
    }
    __syncthreads();

    if (tid < 64) {
        const int orig = base[tid];
        int v = orig;
        #pragma unroll
        for (int d = 1; d < 64; d <<= 1) {
            const int t = __shfl_up(v, d, 64);
            if (tid >= d) v += t;
        }
        base[tid] = v - orig;
    }
    __syncthreads();

    for (int i = tid; i < num_items; i += blockDim.x) {
        const int pos = atomicAdd(&base[(int)s_y0[i]], 1);
        perm[pos] = i;
    }
}

__global__ __launch_bounds__(256) void roi_pool_row_kernel(
    const float* __restrict__ fm,
    const int* __restrict__ rois,
    const int* __restrict__ perm,
    int nw,
    float* __restrict__ out)
{
    // bijective XCD swizzle (nw % 8 == 0): XCD j gets a contiguous y0 band
    const int per = nw >> 3;
    const int b   = blockIdx.x;
    const int sb  = (b & 7) * per + (b >> 3);
    const int item = perm[sb];

    const int py  = item % POOL;
    const int roi = item / POOL;

    const int4 r = *reinterpret_cast<const int4*>(rois + roi * 4);
    const int x = r.x, y = r.y, w = r.z, h = r.w;

    // Legacy-TF bilinear (align_corners=False, no half-pixel centers)
    const float fy = (float)y + (float)py * ((float)h * (1.0f / 14.0f));
    const int   y0 = (int)floorf(fy);
    const int   y1 = min(y0 + 1, y + h - 1);
    const float wy = fy - (float)y0;

    const int c = threadIdx.x;  // float4 lane over channels
    const f4* row0 = reinterpret_cast<const f4*>(fm) + (size_t)(y0 * FMW) * C4 + c;
    const f4* row1 = reinterpret_cast<const f4*>(fm) + (size_t)(y1 * FMW) * C4 + c;
    f4* op = reinterpret_cast<f4*>(out) + (size_t)((roi * POOL + py) * POOL) * C4 + c;

    const float wscale = (float)w * (1.0f / 14.0f);
    const int   xmax   = x + w - 1;

    // ---- software pipeline, 2 deep: loads for px+2 issued while px computes
    // stage A (px), stage B (px+1), incoming (px+2)
    const int bx1p = min(x + 1, xmax);
    f4 a_tl = row0[(size_t)x * C4];
    f4 a_tr = row0[(size_t)bx1p * C4];
    f4 a_bl = row1[(size_t)x * C4];
    f4 a_br = row1[(size_t)bx1p * C4];
    float a_wx = 0.0f;

    const float fx1 = (float)x + wscale;
    const int   bx0 = (int)floorf(fx1);
    const int   bx1 = min(bx0 + 1, xmax);
    f4 b_tl = row0[(size_t)bx0 * C4];
    f4 b_tr = row0[(size_t)bx1 * C4];
    f4 b_bl = row1[(size_t)bx0 * C4];
    f4 b_br = row1[(size_t)bx1 * C4];
    float b_wx = fx1 - (float)bx0;

    #pragma unroll 1
    for (int px = 0; px < POOL - 2; ++px) {
        // issue px+2 loads (8 loads now outstanding ahead of the wait)
        const float fx  = (float)x + (float)(px + 2) * wscale;
        const int   x0  = (int)floorf(fx);
        const int   x1  = min(x0 + 1, xmax);
        const float nwx = fx - (float)x0;
        const f4 n_tl = row0[(size_t)x0 * C4];
        const f4 n_tr = row0[(size_t)x1 * C4];
        const f4 n_bl = row1[(size_t)x0 * C4];
        const f4 n_br = row1[(size_t)x1 * C4];

        // compute + store px (waits only on stage-A loads, 8 ops old)
        const f4 top = a_tl + a_wx * (a_tr - a_tl);
        const f4 bot = a_bl + a_wx * (a_br - a_bl);
        const f4 o   = top + wy * (bot - top);
        op[(size_t)px * C4] = o;

        a_tl = b_tl; a_tr = b_tr; a_bl = b_bl; a_br = b_br; a_wx = b_wx;
        b_tl = n_tl; b_tr = n_tr; b_bl = n_bl; b_br = n_br; b_wx = nwx;
    }
    {
        const f4 top = a_tl + a_wx * (a_tr - a_tl);
        const f4 bot = a_bl + a_wx * (a_br - a_bl);
        const f4 o   = top + wy * (bot - top);
        op[(size_t)(POOL - 2) * C4] = o;
    }
    {
        const f4 top = b_tl + b_wx * (b_tr - b_tl);
        const f4 bot = b_bl + b_wx * (b_br - b_bl);
        const f4 o   = top + wy * (bot - top);
        op[(size_t)(POOL - 1) * C4] = o;
    }
}

// Fallback without permutation (identity order).
__global__ __launch_bounds__(256) void roi_pool_row_kernel_noperm(
    const float* __restrict__ fm,
    const int* __restrict__ rois,
    int nw,
    float* __restrict__ out)
{
    const int sb  = blockIdx.x;
    const int py  = sb % POOL;
    const int roi = sb / POOL;

    const int4 r = *reinterpret_cast<const int4*>(rois + roi * 4);
    const int x = r.x, y = r.y, w = r.z, h = r.w;

    const float fy = (float)y + (float)py * ((float)h * (1.0f / 14.0f));
    const int   y0 = (int)floorf(fy);
    const int   y1 = min(y0 + 1, y + h - 1);
    const float wy = fy - (float)y0;

    const int c = threadIdx.x;
    const f4* row0 = reinterpret_cast<const f4*>(fm) + (size_t)(y0 * FMW) * C4 + c;
    const f4* row1 = reinterpret_cast<const f4*>(fm) + (size_t)(y1 * FMW) * C4 + c;
    f4* op = reinterpret_cast<f4*>(out) + (size_t)((roi * POOL + py) * POOL) * C4 + c;

    const float wscale = (float)w * (1.0f / 14.0f);
    const int   xmax   = x + w - 1;

    for (int px = 0; px < POOL; ++px) {
        const float fx = (float)x + (float)px * wscale;
        const int   x0 = (int)floorf(fx);
        const int   x1 = min(x0 + 1, xmax);
        const float wx = fx - (float)x0;

        const f4 tl = row0[(size_t)x0 * C4];
        const f4 tr = row0[(size_t)x1 * C4];
        const f4 bl = row1[(size_t)x0 * C4];
        const f4 br = row1[(size_t)x1 * C4];

        const f4 top = tl + wx * (tr - tl);
        const f4 bot = bl + wx * (br - bl);
        const f4 o   = top + wy * (bot - top);

        op[(size_t)px * C4] = o;
    }
}

extern "C" void kernel_launch(void* const* d_in, const int* in_sizes, int n_in,
                              void* d_out, int out_size, void* d_ws, size_t ws_size,
                              hipStream_t stream) {
    const float* fm  = (const float*)d_in[0];   // [1,64,64,1024] f32
    const int* rois  = (const int*)d_in[1];     // [1,300,4] i32
    float* out       = (float*)d_out;           // [1,300,14,14,1024] f32

    const int num_rois = in_sizes[1] / 4;       // 300
    const int nw = num_rois * POOL;             // 4200 work items

    if (ws_size >= (size_t)nw * sizeof(int) && (nw & 7) == 0 && nw <= MAX_ITEMS) {
        int* perm = (int*)d_ws;
        sort_items_kernel<<<1, 1024, 0, stream>>>(rois, num_rois, perm);
        roi_pool_row_kernel<<<nw, 256, 0, stream>>>(fm, rois, perm, nw, out);
    } else {
        roi_pool_row_kernel_noperm<<<nw, 256, 0, stream>>>(fm, rois, nw, out);
    }
}

// Round 10
// 52.859 us; speedup vs baseline: 2.2909x; 1.0212x over previous
//
#include <hip/hip_runtime.h>

// RoiPoolingConv: fm [64,64,1024] f32 NHWC, rois [300,4] int32 (x,y,w,h),
// out [300,14,14,1024] f32.
//
//  1. sort_items: counting-sort 4200 (roi,py) items by y0 into perm (d_ws).
//  2. roi_pool_cache_kernel: one block per item, 256 threads x float4 over
//     1024 channels, loop px. y0-sorted + bijective XCD swizzle (L2 read
//     locality). Plain per-px stores (R8: NT stores -6.5us slower).
//     THIS ROUND: monotone 2-column register cache. x0(px) is
//     non-decreasing and c1=min(c0+1,xmax) always, so per px there are
//     exactly 3 wave-uniform cases: keep (0 loads), shift (2), jump (4).
//     Scalar (readfirstlane) conditions -> s_cbranch, loads truly skipped.
//     Cuts L1-port read transactions ~45% (misses pay the port twice).

#define POOL 14
#define FMW 64
#define CH 1024
#define C4 (CH / 4)        // 256 float4 per pixel
#define MAX_ITEMS (300 * POOL)

typedef float f4 __attribute__((ext_vector_type(4)));

__global__ __launch_bounds__(1024) void sort_items_kernel(
    const int* __restrict__ rois, int num_rois, int* __restrict__ perm)
{
    __shared__ int   base[64];
    __shared__ short s_y0[MAX_ITEMS];
    __shared__ int   s_yh[600];          // (y,h) per roi
    const int tid = threadIdx.x;
    const int num_items = num_rois * POOL;

    if (tid < 64) base[tid] = 0;
    for (int i = tid; i < num_rois; i += blockDim.x) {
        s_yh[i * 2]     = rois[i * 4 + 1];
        s_yh[i * 2 + 1] = rois[i * 4 + 3];
    }
    __syncthreads();

    for (int i = tid; i < num_items; i += blockDim.x) {
        const int roi = i / POOL, py = i % POOL;
        const int y = s_yh[roi * 2], h = s_yh[roi * 2 + 1];
        const float fy = (float)y + (float)py * ((float)h * (1.0f / 14.0f));
        const int y0 = (int)floorf(fy) & 63;
        s_y0[i] = (short)y0;
        atomicAdd(&base[y0], 1);
    }
    __syncthreads();

    if (tid < 64) {
        const int orig = base[tid];
        int v = orig;
        #pragma unroll
        for (int d = 1; d < 64; d <<= 1) {
            const int t = __shfl_up(v, d, 64);
            if (tid >= d) v += t;
        }
        base[tid] = v - orig;
    }
    __syncthreads();

    for (int i = tid; i < num_items; i += blockDim.x) {
        const int pos = atomicAdd(&base[(int)s_y0[i]], 1);
        perm[pos] = i;
    }
}

__global__ __launch_bounds__(256) void roi_pool_cache_kernel(
    const float* __restrict__ fm,
    const int* __restrict__ rois,
    const int* __restrict__ perm,
    int nw,
    float* __restrict__ out)
{
    // bijective XCD swizzle (nw % 8 == 0): XCD j gets a contiguous y0 band
    const int per = nw >> 3;
    const int b   = blockIdx.x;
    const int sb  = (b & 7) * per + (b >> 3);
    const int item = __builtin_amdgcn_readfirstlane(perm[sb]);

    const int py  = item % POOL;
    const int roi = item / POOL;

    const int4 r = *reinterpret_cast<const int4*>(rois + roi * 4);
    const int x = __builtin_amdgcn_readfirstlane(r.x);
    const int y = __builtin_amdgcn_readfirstlane(r.y);
    const int w = __builtin_amdgcn_readfirstlane(r.z);
    const int h = __builtin_amdgcn_readfirstlane(r.w);

    // Legacy-TF bilinear (align_corners=False, no half-pixel centers)
    const float fy = (float)y + (float)py * ((float)h * (1.0f / 14.0f));
    const int   y0 = __builtin_amdgcn_readfirstlane((int)floorf(fy));
    const int   y1 = min(y0 + 1, y + h - 1);
    const float wy = fy - (float)y0;

    const int c = threadIdx.x;  // float4 lane over channels
    const f4* row0 = reinterpret_cast<const f4*>(fm) + (size_t)(y0 * FMW) * C4 + c;
    const f4* row1 = reinterpret_cast<const f4*>(fm) + (size_t)(y1 * FMW) * C4 + c;
    f4* op = reinterpret_cast<f4*>(out) + (size_t)((roi * POOL + py) * POOL) * C4 + c;

    const float wscale = (float)w * (1.0f / 14.0f);
    const int   xmax   = x + w - 1;

    // 2-column register cache. Invariant: c1 == min(c0 + 1, xmax);
    // (tl,bl) hold column c0, (tr,br) hold column c1.
    int c0 = x;
    int c1 = min(x + 1, xmax);
    f4 tl = row0[(size_t)c0 * C4];
    f4 bl = row1[(size_t)c0 * C4];
    f4 tr, br;
    if (c1 != c0) { tr = row0[(size_t)c1 * C4]; br = row1[(size_t)c1 * C4]; }
    else          { tr = tl; br = bl; }

    for (int px = 0; px < POOL; ++px) {
        const float fx = (float)x + (float)px * wscale;
        const int   x0 = __builtin_amdgcn_readfirstlane((int)floorf(fx));
        const int   x1 = min(x0 + 1, xmax);
        const float wx = fx - (float)x0;

        if (x0 != c0) {
            if (x0 == c1) { tl = tr; bl = br; }       // shift left by one
            else { tl = row0[(size_t)x0 * C4]; bl = row1[(size_t)x0 * C4]; }
            c0 = x0;
            if (x1 != c1) {
                if (x1 == c0) { tr = tl; br = bl; }   // clamped at xmax
                else { tr = row0[(size_t)x1 * C4]; br = row1[(size_t)x1 * C4]; }
                c1 = x1;
            }
        }
        // else: x1 == min(x0+1,xmax) == c1 by invariant; cache fully valid

        const f4 top = tl + wx * (tr - tl);
        const f4 bot = bl + wx * (br - bl);
        const f4 o   = top + wy * (bot - top);
        op[(size_t)px * C4] = o;                      // plain streaming store
    }
}

// Fallback without permutation (identity order).
__global__ __launch_bounds__(256) void roi_pool_row_kernel_noperm(
    const float* __restrict__ fm,
    const int* __restrict__ rois,
    int nw,
    float* __restrict__ out)
{
    const int sb  = blockIdx.x;
    const int py  = sb % POOL;
    const int roi = sb / POOL;

    const int4 r = *reinterpret_cast<const int4*>(rois + roi * 4);
    const int x = r.x, y = r.y, w = r.z, h = r.w;

    const float fy = (float)y + (float)py * ((float)h * (1.0f / 14.0f));
    const int   y0 = (int)floorf(fy);
    const int   y1 = min(y0 + 1, y + h - 1);
    const float wy = fy - (float)y0;

    const int c = threadIdx.x;
    const f4* row0 = reinterpret_cast<const f4*>(fm) + (size_t)(y0 * FMW) * C4 + c;
    const f4* row1 = reinterpret_cast<const f4*>(fm) + (size_t)(y1 * FMW) * C4 + c;
    f4* op = reinterpret_cast<f4*>(out) + (size_t)((roi * POOL + py) * POOL) * C4 + c;

    const float wscale = (float)w * (1.0f / 14.0f);
    const int   xmax   = x + w - 1;

    for (int px = 0; px < POOL; ++px) {
        const float fx = (float)x + (float)px * wscale;
        const int   x0 = (int)floorf(fx);
        const int   x1 = min(x0 + 1, xmax);
        const float wx = fx - (float)x0;

        const f4 tl = row0[(size_t)x0 * C4];
        const f4 tr = row0[(size_t)x1 * C4];
        const f4 bl = row1[(size_t)x0 * C4];
        const f4 br = row1[(size_t)x1 * C4];

        const f4 top = tl + wx * (tr - tl);
        const f4 bot = bl + wx * (br - bl);
        const f4 o   = top + wy * (bot - top);

        op[(size_t)px * C4] = o;
    }
}

extern "C" void kernel_launch(void* const* d_in, const int* in_sizes, int n_in,
                              void* d_out, int out_size, void* d_ws, size_t ws_size,
                              hipStream_t stream) {
    const float* fm  = (const float*)d_in[0];   // [1,64,64,1024] f32
    const int* rois  = (const int*)d_in[1];     // [1,300,4] i32
    float* out       = (float*)d_out;           // [1,300,14,14,1024] f32

    const int num_rois = in_sizes[1] / 4;       // 300
    const int nw = num_rois * POOL;             // 4200 work items

    if (ws_size >= (size_t)nw * sizeof(int) && (nw & 7) == 0 && nw <= MAX_ITEMS) {
        int* perm = (int*)d_ws;
        sort_items_kernel<<<1, 1024, 0, stream>>>(rois, num_rois, perm);
        roi_pool_cache_kernel<<<nw, 256, 0, stream>>>(fm, rois, perm, nw, out);
    } else {
        roi_pool_row_kernel_noperm<<<nw, 256, 0, stream>>>(fm, rois, nw, out);
    }
}